// Round 3
// baseline (598.712 us; speedup 1.0000x reference)
//
#include <hip/hip_runtime.h>
#include <hip/hip_bf16.h>

// Problem constants (N=64, D=64, H=64, W=64, K=512)
#define VQ_D   64
#define VQ_K   512
#define VQ_HW  4096                 // H*W
#define VQ_M   262144               // N*H*W
#define VQ_LOSS_OFF 16777216
#define VQ_IDX_OFF  16777217

// ---------------------------------------------------------------------------
// Kernel 1: e_sq[k] = sum_d emb[k][d]^2, replicating numpy's pairwise sum
// for n=64 (8 accumulators stride-8, then ((r0+r1)+(r2+r3))+((r4+r5)+(r6+r7))).
// ---------------------------------------------------------------------------
__global__ void vq_prep(const float* __restrict__ emb, float* __restrict__ esq) {
#pragma clang fp contract(off)
    int k = blockIdx.x * 256 + threadIdx.x;
    if (k < VQ_K) {
        const float* e = emb + k * VQ_D;
        float p[VQ_D];
#pragma unroll
        for (int d = 0; d < VQ_D; ++d) p[d] = e[d] * e[d];   // rounded products
        float r[8];
#pragma unroll
        for (int j = 0; j < 8; ++j) r[j] = p[j];
#pragma unroll
        for (int i = 8; i < VQ_D; i += 8)
#pragma unroll
            for (int j = 0; j < 8; ++j) r[j] += p[i + j];
        esq[k] = ((r[0] + r[1]) + (r[2] + r[3])) + ((r[4] + r[5]) + (r[6] + r[7]));
    }
}

// ---------------------------------------------------------------------------
// Kernel 2: main VQ. One thread per spatial point (n,h,w).
// Distance replicates the numpy fp32 reference BITWISE on the argmin path:
//   dist_k = fl( fl(z_sq + e_sq_k) - fl(2*dot_k) )
// with z_sq from numpy pairwise summation and dot_k a sequential fma chain
// (OpenBLAS sgemm microkernel order). Strict < keeps first occurrence.
// ---------------------------------------------------------------------------
__global__ __launch_bounds__(256) void vq_main(
        const float* __restrict__ z_e,
        const float* __restrict__ emb,
        const float* __restrict__ esq,
        float* __restrict__ out,
        double* __restrict__ loss_acc)
{
#pragma clang fp contract(off)
    const int m  = blockIdx.x * 256 + threadIdx.x;   // point index, < VQ_M
    const int n  = m >> 12;                          // m / 4096
    const int hw = m & 4095;

    const float* zp = z_e + (size_t)n * (VQ_D * VQ_HW) + hw;
    float z[VQ_D];
#pragma unroll
    for (int d = 0; d < VQ_D; ++d) z[d] = zp[d * VQ_HW];  // coalesced per d

    // ---- z_sq: numpy pairwise, n=64 path ----
    float p[VQ_D];
#pragma unroll
    for (int d = 0; d < VQ_D; ++d) p[d] = z[d] * z[d];
    float r[8];
#pragma unroll
    for (int j = 0; j < 8; ++j) r[j] = p[j];
#pragma unroll
    for (int i = 8; i < VQ_D; i += 8)
#pragma unroll
        for (int j = 0; j < 8; ++j) r[j] += p[i + j];
    const float zsq = ((r[0] + r[1]) + (r[2] + r[3])) + ((r[4] + r[5]) + (r[6] + r[7]));

    // ---- argmin over K: two independent sequential fma chains per trip ----
    float best = 3.4e38f;
    int   bi   = 0;
    for (int k = 0; k < VQ_K; k += 2) {
        const float* e0 = emb + k * VQ_D;            // wave-uniform -> s_load
        const float* e1 = e0 + VQ_D;
        float a0 = 0.f, a1 = 0.f;
#pragma unroll
        for (int d = 0; d < VQ_D; ++d) {
            a0 = __builtin_fmaf(z[d], e0[d], a0);    // sequential fma chain
            a1 = __builtin_fmaf(z[d], e1[d], a1);
        }
        float t0 = zsq + esq[k];                     // fl(z_sq + e_sq)
        float d0 = t0 - 2.0f * a0;                   // fl(t - 2*dot), 2*dot exact
        float t1 = zsq + esq[k + 1];
        float d1 = t1 - 2.0f * a1;
        if (d0 < best) { best = d0; bi = k; }        // strict <: first occurrence
        if (d1 < best) { best = d1; bi = k + 1; }
    }

    // ---- gather winning row, write z_q + index, accumulate loss ----
    const float* eb = emb + bi * VQ_D;
    float* op = out + (size_t)n * (VQ_D * VQ_HW) + hw;
    float lsum = 0.f;
#pragma unroll
    for (int d = 0; d < VQ_D; ++d) {
        float q = eb[d];
        op[d * VQ_HW] = q;                           // coalesced across lanes
        float diff = z[d] - q;
        lsum = __builtin_fmaf(diff, diff, lsum);
    }

    out[VQ_IDX_OFF + m] = (float)bi;                 // indices as f32 values

    // ---- loss reduction: wave shuffle -> LDS -> one atomic per block ----
    for (int off = 32; off > 0; off >>= 1)
        lsum += __shfl_down(lsum, off, 64);

    __shared__ float wsum[4];
    const int lane = threadIdx.x & 63;
    const int wid  = threadIdx.x >> 6;
    if (lane == 0) wsum[wid] = lsum;
    __syncthreads();
    if (threadIdx.x == 0) {
        float b = wsum[0] + wsum[1] + wsum[2] + wsum[3];
        atomicAdd(loss_acc, (double)b);
    }
}

// ---------------------------------------------------------------------------
// Kernel 3: finalize loss (mean over M*D = 16777216 elements).
// ---------------------------------------------------------------------------
__global__ void vq_fin(const double* __restrict__ loss_acc, float* __restrict__ out) {
    if (threadIdx.x == 0)
        out[VQ_LOSS_OFF] = (float)(*loss_acc / 16777216.0);
}

extern "C" void kernel_launch(void* const* d_in, const int* in_sizes, int n_in,
                              void* d_out, int out_size, void* d_ws, size_t ws_size,
                              hipStream_t stream) {
    const float* z_e = (const float*)d_in[0];
    const float* emb = (const float*)d_in[1];
    float* out = (float*)d_out;

    // ws layout: [0,8) double loss accumulator, [8, 8+2048) float esq[512]
    double* loss_acc = (double*)d_ws;
    float*  esq      = (float*)((char*)d_ws + 8);

    (void)hipMemsetAsync(d_ws, 0, 8, stream);
    vq_prep<<<2, 256, 0, stream>>>(emb, esq);
    vq_main<<<VQ_M / 256, 256, 0, stream>>>(z_e, emb, esq, out, loss_acc);
    vq_fin<<<1, 64, 0, stream>>>(loss_acc, out);
}